// Round 7
// baseline (1104.889 us; speedup 1.0000x reference)
//
#include <hip/hip_runtime.h>

#define VOCAB 12288
#define EMB 128
// R7: strip tiles. Block = 16 consecutive X rows x ALL 12288 cols -> each
// block sweeps a contiguous 768 KB X span sequentially. 768 blocks, all
// co-resident (3 waves/SIMD at <=170 VGPR). MFMA operands SWAPPED
// (A=tgt(j), B=ctx(i)) so C gives lane: i=ln fixed, j=quad*4+r consecutive
// -> X read as float4/lane, 16 rows x 64B dense per wave instr.
#define TI 16
#define NSTRIP (VOCAB / TI)    // 768 blocks
#define WCOLS (VOCAB / 4)      // 3072 cols per wave
#define NCHUNK (WCOLS / 256)   // 12 chunks of 256 cols

typedef unsigned short u16;
typedef __bf16 bf16x8 __attribute__((ext_vector_type(8)));
typedef float f32x4 __attribute__((ext_vector_type(4)));

__device__ __forceinline__ u16 f2bf(float f) {
    unsigned u = __float_as_uint(f);
    u += 0x7FFF + ((u >> 16) & 1);   // round-to-nearest-even
    return (u16)(u >> 16);
}

// hw transcendentals: v_exp_f32 = 2^x, v_log_f32 = log2(x)
__device__ __forceinline__ float hw_exp2(float x) { return __builtin_amdgcn_exp2f(x); }
__device__ __forceinline__ float hw_log2(float x) { return __builtin_amdgcn_logf(x); }

// Kernel 1: zero the output scalar + cast both embedding matrices fp32->bf16 into ws.
__global__ __launch_bounds__(256) void glove_prep(
        const float* __restrict__ tgt, const float* __restrict__ ctx,
        u16* __restrict__ tgtb, u16* __restrict__ ctxb, float* __restrict__ out) {
    int idx = blockIdx.x * 256 + threadIdx.x;
    if (idx == 0) out[0] = 0.0f;
    const int N4 = (VOCAB * EMB) / 4;   // 393216 float4s per matrix
    const float4* __restrict__ s;
    u16* __restrict__ d;
    int k = idx;
    if (k < N4) { s = (const float4*)tgt; d = tgtb; }
    else        { k -= N4; s = (const float4*)ctx; d = ctxb; }
    float4 v = s[k];
    unsigned lo = (unsigned)f2bf(v.x) | ((unsigned)f2bf(v.y) << 16);
    unsigned hi = (unsigned)f2bf(v.z) | ((unsigned)f2bf(v.w) << 16);
    ((uint2*)d)[k] = make_uint2(lo, hi);
}

// Kernel 2: strip kernel. Per block: ctx strip (16x128 bf16, 4 KB) staged to
// LDS once, held in 4 B-operand fragments in regs for the whole kernel.
// Wave w sweeps cols [w*3072, (w+1)*3072) in 12 chunks of 256: per chunk,
// 64 MFMAs (A-frags direct from L2-resident tgtb) -> acc[16] f32x4, then the
// fused epilogue reads X as 16 float4/lane (dense 16rowx64B wave segments,
// monotone in j -> every X row is one sequential DRAM stream).
__global__ __launch_bounds__(256, 3) void glove_main(
        const float* __restrict__ X,
        const u16* __restrict__ ctxb, const u16* __restrict__ tgtb,
        const float* __restrict__ tb, const float* __restrict__ cb,
        float* __restrict__ out, float* __restrict__ partial) {
    __shared__ __bf16 smA[TI * EMB];   // 4 KB ctx strip, xor-swizzled 16B chunks
    __shared__ float red[4];

    const int tid  = threadIdx.x;      // 0..255
    const int lane = tid & 63;
    const int wave = tid >> 6;         // 0..3
    const int quad = lane >> 4;
    const int ln   = lane & 15;

    const int bi = blockIdx.x * TI;    // strip row base

    // Stage ctx strip: 16 rows x 16 chunks of 16B, one per thread.
    // LDS chunk (row, c^row) holds global chunk (row, c) -> conflict-free frag reads.
    {
        int row = tid >> 4;            // 0..15
        int c   = tid & 15;
        uint4 v = *(const uint4*)(ctxb + (size_t)(bi + row) * EMB + c * 8);
        *(uint4*)(smA + row * EMB + (c ^ row) * 8) = v;
    }
    __syncthreads();

    // ctx fragments (B-operand, N-side = i): row = ln, k-chunk = s*4+quad.
    bf16x8 bf[4];
#pragma unroll
    for (int s = 0; s < 4; ++s) {
        int cp = (s * 4 + quad) ^ ln;  // unswizzle
        bf[s] = *(const bf16x8*)(smA + ln * EMB + cp * 8);
    }

    const float cbi = cb[bi + ln];     // i = bi+ln is FIXED per lane
    const float LN2 = 0.69314718055994531f;
    float sum = 0.0f;

    const int jw = wave * WCOLS;

    for (int ch = 0; ch < NCHUNK; ++ch) {
        const int j0 = jw + ch * 256;

        f32x4 acc[16];
#pragma unroll
        for (int n = 0; n < 16; ++n) acc[n] = (f32x4){0.f, 0.f, 0.f, 0.f};

        // dots^T for this 256-col chunk: A-frags (tgt rows j) straight from L2.
#pragma unroll
        for (int n = 0; n < 16; ++n) {
            const u16* ap = tgtb + (size_t)(j0 + n * 16 + ln) * EMB;
#pragma unroll
            for (int s = 0; s < 4; ++s) {
                bf16x8 af = *(const bf16x8*)(ap + (s * 4 + quad) * 8);
                acc[n] = __builtin_amdgcn_mfma_f32_16x16x32_bf16(
                             af, bf[s], acc[n], 0, 0, 0);
            }
        }

        // Fused epilogue. Lane holds (i = bi+ln, j = j0 + n*16 + quad*4 + r):
        // r=0..3 are consecutive j -> one float4 X load per n.
        const float* xrow = X + (size_t)(bi + ln) * VOCAB + j0 + quad * 4;
        const float* tbp  = tb + j0 + quad * 4;
#pragma unroll
        for (int n = 0; n < 16; ++n) {
            f32x4 xq  = __builtin_nontemporal_load((const f32x4*)(xrow + n * 16));
            f32x4 tb4 = *(const f32x4*)(tbp + n * 16);
#pragma unroll
            for (int r = 0; r < 4; ++r) {
                float x  = xq[r];
                float d  = acc[n][r] + tb4[r] + cbi - LN2 * hw_log2(1.0f + x);
                float xs = x * 0.01f;
                float w  = hw_exp2(0.75f * hw_log2(xs));   // xs^0.75; xs=0 -> 0
                w = fminf(w, 1.0f);
                sum = fmaf(w * d, d, sum);
            }
        }
    }

    // wave reduce -> cross-wave via LDS -> one plain store per block
#pragma unroll
    for (int off = 32; off > 0; off >>= 1) sum += __shfl_down(sum, off);

    if (lane == 0) red[wave] = sum;
    __syncthreads();
    if (tid == 0) {
        float v = red[0] + red[1] + red[2] + red[3];
        if (partial) partial[blockIdx.x] = v;   // no same-line contention
        else         atomicAdd(out, v);         // fallback if ws too small
    }
}

// Kernel 3: reduce the 768 per-block partials (3KB, L2-hot) into out[0].
__global__ __launch_bounds__(256) void glove_reduce(
        const float* __restrict__ partial, float* __restrict__ out) {
    int tid = threadIdx.x;
    float s = 0.0f;
    const float4* p4 = (const float4*)partial;
    for (int k = tid; k < NSTRIP / 4; k += 256) {
        float4 v = p4[k];
        s += v.x + v.y + v.z + v.w;
    }
#pragma unroll
    for (int off = 32; off > 0; off >>= 1) s += __shfl_down(s, off);
    __shared__ float red[4];
    if ((tid & 63) == 0) red[tid >> 6] = s;
    __syncthreads();
    if (tid == 0) out[0] = red[0] + red[1] + red[2] + red[3];
}

extern "C" void kernel_launch(void* const* d_in, const int* in_sizes, int n_in,
                              void* d_out, int out_size, void* d_ws, size_t ws_size,
                              hipStream_t stream) {
    const float* X   = (const float*)d_in[0];
    const float* tgt = (const float*)d_in[1];
    const float* ctx = (const float*)d_in[2];
    const float* tb  = (const float*)d_in[3];
    const float* cb  = (const float*)d_in[4];
    float* out = (float*)d_out;

    u16* tgtb = (u16*)d_ws;
    u16* ctxb = tgtb + (size_t)VOCAB * EMB;

    // partial-sum array right after the two bf16 matrices (offset 6291456 B, 16B-aligned)
    const size_t emb_bytes = (size_t)VOCAB * EMB * sizeof(u16) * 2;
    float* partial = nullptr;
    if (ws_size >= emb_bytes + (size_t)NSTRIP * sizeof(float))
        partial = (float*)((char*)d_ws + emb_bytes);

    glove_prep<<<dim3(2 * (VOCAB * EMB / 4) / 256), 256, 0, stream>>>(
        tgt, ctx, tgtb, ctxb, out);
    glove_main<<<dim3(NSTRIP), 256, 0, stream>>>(
        X, ctxb, tgtb, tb, cb, out, partial);
    if (partial)
        glove_reduce<<<dim3(1), 256, 0, stream>>>(partial, out);
}